// Round 2
// baseline (352.342 us; speedup 1.0000x reference)
//
#include <hip/hip_runtime.h>
#include <hip/hip_bf16.h>
#include <math.h>

// Problem constants
#define NQ1 1001      // NQ+1 rows in embed tables
#define KK 5
#define MM 50
#define KD 64
#define VD 64
#define SD 50
#define BB 512
#define SS 500

#define NW 4          // waves per scan block
#define MPW 16        // memory slots per wave (padded 64 total)

// Workspace layout (in floats)
#define OFF_ATTN   0                      // [1001][64]  attn rows, padded to 64 (cols 50..63 = 0)
#define OFF_SQ     (OFF_ATTN + NQ1*64)    // [1001][64]  q_embed @ Ws[64:128], padded
#define OFF_ETAB   (OFF_SQ   + NQ1*64)    // [5005][64]
#define OFF_ADTAB  (OFF_ETAB + NQ1*KK*64) // [5005][64]
#define OFF_WST    (OFF_ADTAB+ NQ1*KK*64) // [50][64] transposed top of Ws
#define OFF_WCT    (OFF_WST  + SD*64)     // [5][50] transposed Wc (pad to 256)
#define OFF_READS  (OFF_WCT  + 256)       // [512*500][64]

// ---------------- kernel 1: per-question tables (attn softmax + Sq) + transposes ----------------
__global__ __launch_bounds__(64) void k_qtab(
    const float* __restrict__ qtab, const float* __restrict__ keymem,
    const float* __restrict__ Ws, const float* __restrict__ Wc,
    float* __restrict__ attn_tab, float* __restrict__ sq_tab,
    float* __restrict__ WsT, float* __restrict__ WcT) {
  const int q = blockIdx.x;
  const int t = threadIdx.x;

  if (q == NQ1) {  // extra block: transposes
    for (int idx = t; idx < 64 * SD; idx += 64) {
      int i = idx / SD, j = idx % SD;          // Ws[i][j], i<64 (read part)
      WsT[j * 64 + i] = Ws[idx];
    }
    for (int idx = t; idx < SD * KK; idx += 64) {
      int j = idx / KK, c = idx % KK;          // Wc[j][c]
      WcT[c * SD + j] = Wc[idx];
    }
    return;
  }

  __shared__ float qe[64];
  qe[t] = qtab[q * KD + t];
  __syncthreads();

  float dot = 0.f;
  if (t < MM) {
#pragma unroll
    for (int i = 0; i < KD; ++i) dot = fmaf(qe[i], keymem[t * KD + i], dot);
  }
  float xv = (t < MM) ? dot : -1e30f;
#pragma unroll
  for (int off = 32; off; off >>= 1) xv = fmaxf(xv, __shfl_xor(xv, off));
  float p = (t < MM) ? __expf(dot - xv) : 0.f;
  float sum = p;
#pragma unroll
  for (int off = 32; off; off >>= 1) sum += __shfl_xor(sum, off);
  attn_tab[q * 64 + t] = p / sum;   // pad lanes (t>=50) write 0

  float sq = 0.f;
  if (t < SD) {
#pragma unroll
    for (int i = 0; i < KD; ++i) sq = fmaf(qe[i], Ws[(64 + i) * SD + t], sq);
  }
  sq_tab[q * 64 + t] = (t < SD) ? sq : 0.f;
}

// ---------------- kernel 2: per-(q,r) erase/add tables ----------------
__global__ __launch_bounds__(64) void k_evtab(
    const float* __restrict__ itab, const float* __restrict__ Wv,
    const float* __restrict__ bv, const float* __restrict__ We,
    const float* __restrict__ be, const float* __restrict__ Wa,
    const float* __restrict__ ba,
    float* __restrict__ e_tab, float* __restrict__ ad_tab) {
  const int qr = blockIdx.x;
  const int q = qr / KK, r = qr % KK;
  const int v = threadIdx.x;
  __shared__ float item[64];
  __shared__ float ves[64];
  item[v] = itab[q * KD + v];
  __syncthreads();

  float ve = bv[v];
#pragma unroll
  for (int i = 0; i < KD; ++i) ve = fmaf(item[i], Wv[i * VD + v], ve);
#pragma unroll
  for (int k = 0; k < KK; ++k) {
    float rf = fmaxf(0.f, 1.f - fabsf((float)k - (float)r) * 0.25f);
    ve = fmaf(rf, Wv[(KD + k) * VD + v], ve);
  }
  ves[v] = ve;
  __syncthreads();

  float se = be[v], sa = ba[v];
#pragma unroll
  for (int i = 0; i < VD; ++i) {
    float x = ves[i];
    se = fmaf(x, We[i * VD + v], se);
    sa = fmaf(x, Wa[i * VD + v], sa);
  }
  e_tab[qr * 64 + v] = 1.f / (1.f + __expf(-se));
  float ex = __expf(2.f * sa);
  ad_tab[qr * 64 + v] = (ex - 1.f) / (ex + 1.f);
}

// ---------------- kernel 3: sequential scan, 4 waves per batch (M split) ----------------
__global__ __launch_bounds__(NW * 64) void k_scan(
    const int* __restrict__ qs, const int* __restrict__ rs,
    const float* __restrict__ attn_tab, const float* __restrict__ e_tab,
    const float* __restrict__ ad_tab, const float* __restrict__ init_vm,
    float* __restrict__ reads) {
  const int b = blockIdx.x;
  const int tid = threadIdx.x;
  const int w = tid >> 6;       // wave id 0..3
  const int v = tid & 63;       // value column
  const int mbase = w * MPW;

  __shared__ float part[2][NW * 64];

  float vm[MPW];
#pragma unroll
  for (int i = 0; i < MPW; ++i) {
    int m = mbase + i;
    vm[i] = (m < MM) ? init_vm[m * VD + v] : 0.f;
  }

  const int* __restrict__ qb = qs + b * SS;
  const int* __restrict__ rb = rs + b * SS;

  int q1 = qb[0], r1 = rb[0];
  int q2 = qb[1], r2 = rb[1];

  const float* __restrict__ ar0 = attn_tab + q1 * 64 + mbase;
  float4 acur[4];
  acur[0] = *(const float4*)(ar0);
  acur[1] = *(const float4*)(ar0 + 4);
  acur[2] = *(const float4*)(ar0 + 8);
  acur[3] = *(const float4*)(ar0 + 12);
  float e1 = e_tab[(q1 * KK + r1) * 64 + v];
  float ad1 = ad_tab[(q1 * KK + r1) * 64 + v];

  float* __restrict__ outp = reads + ((size_t)b * SS) * 64 + v;

  for (int s = 0; s < SS; ++s) {
    // ---- prefetch step s+1 (q2 safe: 0 when past end, row 0 exists) ----
    const float* __restrict__ arn = attn_tab + q2 * 64 + mbase;
    float4 anxt[4];
    anxt[0] = *(const float4*)(arn);
    anxt[1] = *(const float4*)(arn + 4);
    anxt[2] = *(const float4*)(arn + 8);
    anxt[3] = *(const float4*)(arn + 12);
    float e2 = e_tab[(q2 * KK + r2) * 64 + v];
    float ad2 = ad_tab[(q2 * KK + r2) * 64 + v];
    int idx2 = (s + 2 < SS) ? (s + 2) : (SS - 1);
    int q3 = qb[idx2], r3 = rb[idx2];
    if (s + 2 >= SS) { q3 = 0; r3 = 0; }

    // ---- compute step s ----
    float acc = 0.f;
#pragma unroll
    for (int g = 0; g < 4; ++g) {
      float a0 = acur[g].x, a1 = acur[g].y, a2 = acur[g].z, a3 = acur[g].w;
      acc = fmaf(a0, vm[4 * g + 0], acc);
      vm[4 * g + 0] = fmaf(a0, fmaf(-e1, vm[4 * g + 0], ad1), vm[4 * g + 0]);
      acc = fmaf(a1, vm[4 * g + 1], acc);
      vm[4 * g + 1] = fmaf(a1, fmaf(-e1, vm[4 * g + 1], ad1), vm[4 * g + 1]);
      acc = fmaf(a2, vm[4 * g + 2], acc);
      vm[4 * g + 2] = fmaf(a2, fmaf(-e1, vm[4 * g + 2], ad1), vm[4 * g + 2]);
      acc = fmaf(a3, vm[4 * g + 3], acc);
      vm[4 * g + 3] = fmaf(a3, fmaf(-e1, vm[4 * g + 3], ad1), vm[4 * g + 3]);
    }
    part[s & 1][w * 64 + v] = acc;

    // ---- store step s-1 (partials synced by previous barrier), round-robin wave ----
    if (s > 0 && w == ((s - 1) & 3)) {
      const float* __restrict__ pp = part[(s - 1) & 1];
      float sum = (pp[v] + pp[64 + v]) + (pp[128 + v] + pp[192 + v]);
      outp[(size_t)(s - 1) * 64] = sum;
    }
    __syncthreads();

    q1 = q2; r1 = r2; q2 = q3; r2 = r3;
    acur[0] = anxt[0]; acur[1] = anxt[1]; acur[2] = anxt[2]; acur[3] = anxt[3];
    e1 = e2; ad1 = ad2;
  }

  // ---- final step's sum ----
  {
    const int s = SS - 1;
    if (w == (s & 3)) {
      const float* __restrict__ pp = part[s & 1];
      float sum = (pp[v] + pp[64 + v]) + (pp[128 + v] + pp[192 + v]);
      outp[(size_t)s * 64] = sum;
    }
  }
}

// ---------------- kernel 4: summary + logits + softmax ----------------
__global__ __launch_bounds__(64) void k_out(
    const float* __restrict__ reads, const int* __restrict__ qs,
    const float* __restrict__ sq_tab, const float* __restrict__ WsT,
    const float* __restrict__ bs, const float* __restrict__ WcT,
    const float* __restrict__ bc,
    float* __restrict__ out_logits, float* __restrict__ out_probs) {
  __shared__ float xs[64 * 65];
  const int lane = threadIdx.x;
  const long rowbase = (long)blockIdx.x * 64;
  const float* __restrict__ src = reads + rowbase * 64;

  // stage 64 rows x 64 cols into LDS with +1 pad (conflict-free row reads)
#pragma unroll 8
  for (int it = 0; it < 64; ++it)
    xs[it * 65 + lane] = src[it * 64 + lane];
  __syncthreads();

  float x[64];
#pragma unroll
  for (int i = 0; i < 64; ++i) x[i] = xs[lane * 65 + i];

  const long row = rowbase + lane;
  const int q = qs[row];
  const float* __restrict__ sqrow = sq_tab + (long)q * 64;

  float sm[SD];
#pragma unroll
  for (int j = 0; j < SD; ++j) {
    float acc = bs[j] + sqrow[j];
    const float* __restrict__ wrow = WsT + j * 64;  // uniform -> s_load
#pragma unroll
    for (int i = 0; i < 64; ++i) acc = fmaf(x[i], wrow[i], acc);
    float ex = __expf(2.f * acc);
    sm[j] = (ex - 1.f) / (ex + 1.f);
  }

  float lg[KK];
#pragma unroll
  for (int c = 0; c < KK; ++c) {
    float acc = bc[c];
    const float* __restrict__ wrow = WcT + c * SD;  // uniform -> s_load
#pragma unroll
    for (int j = 0; j < SD; ++j) acc = fmaf(sm[j], wrow[j], acc);
    lg[c] = acc;
  }

  float mx = lg[0];
#pragma unroll
  for (int c = 1; c < KK; ++c) mx = fmaxf(mx, lg[c]);
  float p[KK], sum = 0.f;
#pragma unroll
  for (int c = 0; c < KK; ++c) { p[c] = __expf(lg[c] - mx); sum += p[c]; }
  float inv = 1.f / sum;
#pragma unroll
  for (int c = 0; c < KK; ++c) {
    out_logits[row * KK + c] = lg[c];
    out_probs[row * KK + c] = p[c] * inv;
  }
}

extern "C" void kernel_launch(void* const* d_in, const int* in_sizes, int n_in,
                              void* d_out, int out_size, void* d_ws, size_t ws_size,
                              hipStream_t stream) {
  const int*   questions  = (const int*)  d_in[0];
  const int*   responses  = (const int*)  d_in[1];
  const float* q_table    = (const float*)d_in[2];
  const float* item_table = (const float*)d_in[3];
  const float* Wv         = (const float*)d_in[4];
  const float* bv         = (const float*)d_in[5];
  const float* key_mem    = (const float*)d_in[6];
  const float* init_vm    = (const float*)d_in[7];
  const float* We         = (const float*)d_in[8];
  const float* be         = (const float*)d_in[9];
  const float* Wa         = (const float*)d_in[10];
  const float* ba         = (const float*)d_in[11];
  const float* Ws         = (const float*)d_in[12];
  const float* bs         = (const float*)d_in[13];
  const float* Wc         = (const float*)d_in[14];
  const float* bc         = (const float*)d_in[15];

  float* ws       = (float*)d_ws;
  float* attn_tab = ws + OFF_ATTN;
  float* sq_tab   = ws + OFF_SQ;
  float* e_tab    = ws + OFF_ETAB;
  float* ad_tab   = ws + OFF_ADTAB;
  float* WsT      = ws + OFF_WST;
  float* WcT      = ws + OFF_WCT;
  float* reads    = ws + OFF_READS;

  float* out_logits = (float*)d_out;
  float* out_probs  = out_logits + (size_t)BB * SS * KK;

  hipLaunchKernelGGL(k_qtab, dim3(NQ1 + 1), dim3(64), 0, stream,
                     q_table, key_mem, Ws, Wc, attn_tab, sq_tab, WsT, WcT);
  hipLaunchKernelGGL(k_evtab, dim3(NQ1 * KK), dim3(64), 0, stream,
                     item_table, Wv, bv, We, be, Wa, ba, e_tab, ad_tab);
  hipLaunchKernelGGL(k_scan, dim3(BB), dim3(NW * 64), 0, stream,
                     questions, responses, attn_tab, e_tab, ad_tab, init_vm, reads);
  hipLaunchKernelGGL(k_out, dim3(BB * SS / 64), dim3(64), 0, stream,
                     reads, questions, sq_tab, WsT, bs, WcT, bc,
                     out_logits, out_probs);
}

// Round 3
// 275.213 us; speedup vs baseline: 1.2803x; 1.2803x over previous
//
#include <hip/hip_runtime.h>
#include <hip/hip_bf16.h>
#include <math.h>

// Problem constants
#define NQ1 1001      // NQ+1 rows in embed tables
#define KK 5
#define MM 50
#define KD 64
#define VD 64
#define SD 50
#define BB 512
#define SS 500

#define NW 4          // waves per scan block
#define MPW 16        // memory slots per wave (padded 64 total)
#define WIN 16        // scan steps per flush window

// Workspace layout (in floats)
#define OFF_ATTN   0                      // [1001][64]  attn rows, padded to 64 (cols 50..63 = 0)
#define OFF_SQ     (OFF_ATTN + NQ1*64)    // [1001][64]  q_embed @ Ws[64:128], padded
#define OFF_ETAB   (OFF_SQ   + NQ1*64)    // [5005][64]
#define OFF_ADTAB  (OFF_ETAB + NQ1*KK*64) // [5005][64]
#define OFF_WST    (OFF_ADTAB+ NQ1*KK*64) // [50][64] transposed top of Ws
#define OFF_WCT    (OFF_WST  + SD*64)     // [5][50] transposed Wc (pad to 256)
#define OFF_READS  (OFF_WCT  + 256)       // [512*500][64]

// ---------------- kernel 1: per-question tables (attn softmax + Sq) + transposes ----------------
__global__ __launch_bounds__(64) void k_qtab(
    const float* __restrict__ qtab, const float* __restrict__ keymem,
    const float* __restrict__ Ws, const float* __restrict__ Wc,
    float* __restrict__ attn_tab, float* __restrict__ sq_tab,
    float* __restrict__ WsT, float* __restrict__ WcT) {
  const int q = blockIdx.x;
  const int t = threadIdx.x;

  if (q == NQ1) {  // extra block: transposes
    for (int idx = t; idx < 64 * SD; idx += 64) {
      int i = idx / SD, j = idx % SD;          // Ws[i][j], i<64 (read part)
      WsT[j * 64 + i] = Ws[idx];
    }
    for (int idx = t; idx < SD * KK; idx += 64) {
      int j = idx / KK, c = idx % KK;          // Wc[j][c]
      WcT[c * SD + j] = Wc[idx];
    }
    return;
  }

  __shared__ float qe[64];
  qe[t] = qtab[q * KD + t];
  __syncthreads();

  float dot = 0.f;
  if (t < MM) {
#pragma unroll
    for (int i = 0; i < KD; ++i) dot = fmaf(qe[i], keymem[t * KD + i], dot);
  }
  float xv = (t < MM) ? dot : -1e30f;
#pragma unroll
  for (int off = 32; off; off >>= 1) xv = fmaxf(xv, __shfl_xor(xv, off));
  float p = (t < MM) ? __expf(dot - xv) : 0.f;
  float sum = p;
#pragma unroll
  for (int off = 32; off; off >>= 1) sum += __shfl_xor(sum, off);
  attn_tab[q * 64 + t] = p / sum;   // pad lanes (t>=50) write 0

  float sq = 0.f;
  if (t < SD) {
#pragma unroll
    for (int i = 0; i < KD; ++i) sq = fmaf(qe[i], Ws[(64 + i) * SD + t], sq);
  }
  sq_tab[q * 64 + t] = (t < SD) ? sq : 0.f;
}

// ---------------- kernel 2: per-(q,r) erase/add tables ----------------
__global__ __launch_bounds__(64) void k_evtab(
    const float* __restrict__ itab, const float* __restrict__ Wv,
    const float* __restrict__ bv, const float* __restrict__ We,
    const float* __restrict__ be, const float* __restrict__ Wa,
    const float* __restrict__ ba,
    float* __restrict__ e_tab, float* __restrict__ ad_tab) {
  const int qr = blockIdx.x;
  const int q = qr / KK, r = qr % KK;
  const int v = threadIdx.x;
  __shared__ float item[64];
  __shared__ float ves[64];
  item[v] = itab[q * KD + v];
  __syncthreads();

  float ve = bv[v];
#pragma unroll
  for (int i = 0; i < KD; ++i) ve = fmaf(item[i], Wv[i * VD + v], ve);
#pragma unroll
  for (int k = 0; k < KK; ++k) {
    float rf = fmaxf(0.f, 1.f - fabsf((float)k - (float)r) * 0.25f);
    ve = fmaf(rf, Wv[(KD + k) * VD + v], ve);
  }
  ves[v] = ve;
  __syncthreads();

  float se = be[v], sa = ba[v];
#pragma unroll
  for (int i = 0; i < VD; ++i) {
    float x = ves[i];
    se = fmaf(x, We[i * VD + v], se);
    sa = fmaf(x, Wa[i * VD + v], sa);
  }
  e_tab[qr * 64 + v] = 1.f / (1.f + __expf(-se));
  float ex = __expf(2.f * sa);
  ad_tab[qr * 64 + v] = (ex - 1.f) / (ex + 1.f);
}

// ---------------- kernel 3: sequential scan, 4 waves (M split), no per-step sync ----------------
__global__ __launch_bounds__(NW * 64) void k_scan(
    const int* __restrict__ qs, const int* __restrict__ rs,
    const float* __restrict__ attn_tab, const float* __restrict__ e_tab,
    const float* __restrict__ ad_tab, const float* __restrict__ init_vm,
    float* __restrict__ reads) {
  const int b = blockIdx.x;
  const int tid = threadIdx.x;
  const int w = tid >> 6;       // wave id 0..3
  const int v = tid & 63;       // value column
  const int mbase = w * MPW;

  __shared__ int2  sidx[SS];            // per step: (attn float-offset, e/ad float-offset)
  __shared__ float red[WIN][NW][64];    // per-wave partial read sums

  // stage indices once (removes index loads from the recurrence chain)
  const int* __restrict__ qb = qs + b * SS;
  const int* __restrict__ rb = rs + b * SS;
  for (int s = tid; s < SS; s += NW * 64) {
    int q = qb[s];
    int r = rb[s];
    sidx[s] = make_int2(q * 64, (q * KK + r) * 64);
  }

  float vm[MPW];
#pragma unroll
  for (int i = 0; i < MPW; ++i) {
    int m = mbase + i;
    vm[i] = (m < MM) ? init_vm[m * VD + v] : 0.f;
  }
  __syncthreads();

  // ---- 2-deep prefetch ring (slot A = even steps, slot B = odd steps) ----
  int2 iA = sidx[0];
  int2 iB = sidx[1];
  float4 aA[4], aB[4];
  {
    const float* pa = attn_tab + iA.x + mbase;
    aA[0] = *(const float4*)(pa);      aA[1] = *(const float4*)(pa + 4);
    aA[2] = *(const float4*)(pa + 8);  aA[3] = *(const float4*)(pa + 12);
  }
  float eA = e_tab[iA.y + v], adA = ad_tab[iA.y + v];
  {
    const float* pb = attn_tab + iB.x + mbase;
    aB[0] = *(const float4*)(pb);      aB[1] = *(const float4*)(pb + 4);
    aB[2] = *(const float4*)(pb + 8);  aB[3] = *(const float4*)(pb + 12);
  }
  float eB = e_tab[iB.y + v], adB = ad_tab[iB.y + v];

  float* __restrict__ outp = reads + (size_t)b * SS * 64;

  for (int s0 = 0; s0 < SS; s0 += 2) {
    // ================= step s0 (slot A) =================
    {
      int sn = s0 + 2;
      int2 in2 = sidx[(sn < SS) ? sn : 0];
      float acc0 = 0.f, acc1 = 0.f;
#pragma unroll
      for (int g = 0; g < 4; ++g) {
        float a0 = aA[g].x, a1 = aA[g].y, a2 = aA[g].z, a3 = aA[g].w;
        acc0 = fmaf(a0, vm[4 * g + 0], acc0);
        vm[4 * g + 0] = fmaf(a0, fmaf(-eA, vm[4 * g + 0], adA), vm[4 * g + 0]);
        acc1 = fmaf(a1, vm[4 * g + 1], acc1);
        vm[4 * g + 1] = fmaf(a1, fmaf(-eA, vm[4 * g + 1], adA), vm[4 * g + 1]);
        acc0 = fmaf(a2, vm[4 * g + 2], acc0);
        vm[4 * g + 2] = fmaf(a2, fmaf(-eA, vm[4 * g + 2], adA), vm[4 * g + 2]);
        acc1 = fmaf(a3, vm[4 * g + 3], acc1);
        vm[4 * g + 3] = fmaf(a3, fmaf(-eA, vm[4 * g + 3], adA), vm[4 * g + 3]);
      }
      red[s0 & (WIN - 1)][w][v] = acc0 + acc1;
      // refill slot A for step s0+2
      const float* pa = attn_tab + in2.x + mbase;
      aA[0] = *(const float4*)(pa);      aA[1] = *(const float4*)(pa + 4);
      aA[2] = *(const float4*)(pa + 8);  aA[3] = *(const float4*)(pa + 12);
      eA = e_tab[in2.y + v];
      adA = ad_tab[in2.y + v];
    }

    // ================= step s0+1 (slot B) =================
    {
      int sn = s0 + 3;
      int2 in2 = sidx[(sn < SS) ? sn : 0];
      float acc0 = 0.f, acc1 = 0.f;
#pragma unroll
      for (int g = 0; g < 4; ++g) {
        float a0 = aB[g].x, a1 = aB[g].y, a2 = aB[g].z, a3 = aB[g].w;
        acc0 = fmaf(a0, vm[4 * g + 0], acc0);
        vm[4 * g + 0] = fmaf(a0, fmaf(-eB, vm[4 * g + 0], adB), vm[4 * g + 0]);
        acc1 = fmaf(a1, vm[4 * g + 1], acc1);
        vm[4 * g + 1] = fmaf(a1, fmaf(-eB, vm[4 * g + 1], adB), vm[4 * g + 1]);
        acc0 = fmaf(a2, vm[4 * g + 2], acc0);
        vm[4 * g + 2] = fmaf(a2, fmaf(-eB, vm[4 * g + 2], adB), vm[4 * g + 2]);
        acc1 = fmaf(a3, vm[4 * g + 3], acc1);
        vm[4 * g + 3] = fmaf(a3, fmaf(-eB, vm[4 * g + 3], adB), vm[4 * g + 3]);
      }
      red[(s0 + 1) & (WIN - 1)][w][v] = acc0 + acc1;
      // refill slot B for step s0+3
      const float* pb = attn_tab + in2.x + mbase;
      aB[0] = *(const float4*)(pb);      aB[1] = *(const float4*)(pb + 4);
      aB[2] = *(const float4*)(pb + 8);  aB[3] = *(const float4*)(pb + 12);
      eB = e_tab[in2.y + v];
      adB = ad_tab[in2.y + v];
    }

    // ================= flush window (once per 16 steps) =================
    if (((s0 + 1) & (WIN - 1)) == (WIN - 1)) {
      __syncthreads();
      const int r = tid >> 4;            // 0..15 window row
      const int c = (tid & 15) * 4;      // 0..60 column base
      float4 x0 = *(const float4*)&red[r][0][c];
      float4 x1 = *(const float4*)&red[r][1][c];
      float4 x2 = *(const float4*)&red[r][2][c];
      float4 x3 = *(const float4*)&red[r][3][c];
      float4 o;
      o.x = (x0.x + x1.x) + (x2.x + x3.x);
      o.y = (x0.y + x1.y) + (x2.y + x3.y);
      o.z = (x0.z + x1.z) + (x2.z + x3.z);
      o.w = (x0.w + x1.w) + (x2.w + x3.w);
      *(float4*)(outp + (size_t)(s0 - 14 + r) * 64 + c) = o;
      __syncthreads();
    }
  }

  // ---- tail rows (SS % WIN = 4): steps 496..499 ----
  __syncthreads();
  {
    const int r = tid >> 4;
    const int c = (tid & 15) * 4;
    if (r < (SS & (WIN - 1))) {
      float4 x0 = *(const float4*)&red[r][0][c];
      float4 x1 = *(const float4*)&red[r][1][c];
      float4 x2 = *(const float4*)&red[r][2][c];
      float4 x3 = *(const float4*)&red[r][3][c];
      float4 o;
      o.x = (x0.x + x1.x) + (x2.x + x3.x);
      o.y = (x0.y + x1.y) + (x2.y + x3.y);
      o.z = (x0.z + x1.z) + (x2.z + x3.z);
      o.w = (x0.w + x1.w) + (x2.w + x3.w);
      *(float4*)(outp + (size_t)((SS & ~(WIN - 1)) + r) * 64 + c) = o;
    }
  }
}

// ---------------- kernel 4: summary + logits + softmax ----------------
__global__ __launch_bounds__(64) void k_out(
    const float* __restrict__ reads, const int* __restrict__ qs,
    const float* __restrict__ sq_tab, const float* __restrict__ WsT,
    const float* __restrict__ bs, const float* __restrict__ WcT,
    const float* __restrict__ bc,
    float* __restrict__ out_logits, float* __restrict__ out_probs) {
  __shared__ float xs[64 * 65];
  const int lane = threadIdx.x;
  const long rowbase = (long)blockIdx.x * 64;
  const float* __restrict__ src = reads + rowbase * 64;

#pragma unroll 8
  for (int it = 0; it < 64; ++it)
    xs[it * 65 + lane] = src[it * 64 + lane];
  __syncthreads();

  float x[64];
#pragma unroll
  for (int i = 0; i < 64; ++i) x[i] = xs[lane * 65 + i];

  const long row = rowbase + lane;
  const int q = qs[row];
  const float* __restrict__ sqrow = sq_tab + (long)q * 64;

  float sm[SD];
#pragma unroll
  for (int j = 0; j < SD; ++j) {
    float acc = bs[j] + sqrow[j];
    const float* __restrict__ wrow = WsT + j * 64;  // uniform -> s_load
#pragma unroll
    for (int i = 0; i < 64; ++i) acc = fmaf(x[i], wrow[i], acc);
    float ex = __expf(2.f * acc);
    sm[j] = (ex - 1.f) / (ex + 1.f);
  }

  float lg[KK];
#pragma unroll
  for (int c = 0; c < KK; ++c) {
    float acc = bc[c];
    const float* __restrict__ wrow = WcT + c * SD;  // uniform -> s_load
#pragma unroll
    for (int j = 0; j < SD; ++j) acc = fmaf(sm[j], wrow[j], acc);
    lg[c] = acc;
  }

  float mx = lg[0];
#pragma unroll
  for (int c = 1; c < KK; ++c) mx = fmaxf(mx, lg[c]);
  float p[KK], sum = 0.f;
#pragma unroll
  for (int c = 0; c < KK; ++c) { p[c] = __expf(lg[c] - mx); sum += p[c]; }
  float inv = 1.f / sum;
#pragma unroll
  for (int c = 0; c < KK; ++c) {
    out_logits[row * KK + c] = lg[c];
    out_probs[row * KK + c] = p[c] * inv;
  }
}

extern "C" void kernel_launch(void* const* d_in, const int* in_sizes, int n_in,
                              void* d_out, int out_size, void* d_ws, size_t ws_size,
                              hipStream_t stream) {
  const int*   questions  = (const int*)  d_in[0];
  const int*   responses  = (const int*)  d_in[1];
  const float* q_table    = (const float*)d_in[2];
  const float* item_table = (const float*)d_in[3];
  const float* Wv         = (const float*)d_in[4];
  const float* bv         = (const float*)d_in[5];
  const float* key_mem    = (const float*)d_in[6];
  const float* init_vm    = (const float*)d_in[7];
  const float* We         = (const float*)d_in[8];
  const float* be         = (const float*)d_in[9];
  const float* Wa         = (const float*)d_in[10];
  const float* ba         = (const float*)d_in[11];
  const float* Ws         = (const float*)d_in[12];
  const float* bs         = (const float*)d_in[13];
  const float* Wc         = (const float*)d_in[14];
  const float* bc         = (const float*)d_in[15];

  float* ws       = (float*)d_ws;
  float* attn_tab = ws + OFF_ATTN;
  float* sq_tab   = ws + OFF_SQ;
  float* e_tab    = ws + OFF_ETAB;
  float* ad_tab   = ws + OFF_ADTAB;
  float* WsT      = ws + OFF_WST;
  float* WcT      = ws + OFF_WCT;
  float* reads    = ws + OFF_READS;

  float* out_logits = (float*)d_out;
  float* out_probs  = out_logits + (size_t)BB * SS * KK;

  hipLaunchKernelGGL(k_qtab, dim3(NQ1 + 1), dim3(64), 0, stream,
                     q_table, key_mem, Ws, Wc, attn_tab, sq_tab, WsT, WcT);
  hipLaunchKernelGGL(k_evtab, dim3(NQ1 * KK), dim3(64), 0, stream,
                     item_table, Wv, bv, We, be, Wa, ba, e_tab, ad_tab);
  hipLaunchKernelGGL(k_scan, dim3(BB), dim3(NW * 64), 0, stream,
                     questions, responses, attn_tab, e_tab, ad_tab, init_vm, reads);
  hipLaunchKernelGGL(k_out, dim3(BB * SS / 64), dim3(64), 0, stream,
                     reads, questions, sq_tab, WsT, bs, WcT, bc,
                     out_logits, out_probs);
}

// Round 4
// 234.212 us; speedup vs baseline: 1.5044x; 1.1751x over previous
//
#include <hip/hip_runtime.h>
#include <hip/hip_bf16.h>
#include <math.h>

// Problem constants
#define NQ1 1001      // NQ+1 rows in embed tables
#define KK 5
#define MM 50
#define KD 64
#define VD 64
#define SD 50
#define BB 512
#define SS 500

#define NW 8          // waves per scan block
#define MPW 8         // memory slots per wave (padded 64 total)
#define WIN 16        // scan steps per flush window

// Workspace layout (in floats)
#define OFF_ATTN   0                        // [1001][64] attn rows, cols 50..63 = 0
#define OFF_SQ     (OFF_ATTN + NQ1*64)      // [1001][64] q_embed @ Ws[64:128]
#define OFF_EAD    (OFF_SQ   + NQ1*64)      // [5005][128] interleaved (e,ad) per v
#define OFF_WST    (OFF_EAD  + NQ1*KK*128)  // [50][64] transposed top of Ws
#define OFF_WCT    (OFF_WST  + SD*64)       // [5][50] transposed Wc (pad to 256)
#define OFF_READS  (OFF_WCT  + 256)         // [512*500][64]

#define LGKM_BARRIER() asm volatile("s_waitcnt lgkmcnt(0)\n\ts_barrier" ::: "memory")

// ---------------- kernel 1: all tables (qtab softmax+Sq, transposes, ead) ----------------
__global__ __launch_bounds__(64) void k_tabs(
    const float* __restrict__ qtab, const float* __restrict__ itab,
    const float* __restrict__ keymem,
    const float* __restrict__ Wv, const float* __restrict__ bv,
    const float* __restrict__ We, const float* __restrict__ be,
    const float* __restrict__ Wa, const float* __restrict__ ba,
    const float* __restrict__ Ws, const float* __restrict__ Wc,
    float* __restrict__ attn_tab, float* __restrict__ sq_tab,
    float* __restrict__ ead_tab, float* __restrict__ WsT, float* __restrict__ WcT) {
  const int bid = blockIdx.x;
  const int t = threadIdx.x;

  if (bid < NQ1) {  // ---- per-question: attn softmax row + sq row ----
    const int q = bid;
    __shared__ float qe[64];
    qe[t] = qtab[q * KD + t];
    __syncthreads();

    float dot = 0.f;
    if (t < MM) {
#pragma unroll
      for (int i = 0; i < KD; ++i) dot = fmaf(qe[i], keymem[t * KD + i], dot);
    }
    float xv = (t < MM) ? dot : -1e30f;
#pragma unroll
    for (int off = 32; off; off >>= 1) xv = fmaxf(xv, __shfl_xor(xv, off));
    float p = (t < MM) ? __expf(dot - xv) : 0.f;
    float sum = p;
#pragma unroll
    for (int off = 32; off; off >>= 1) sum += __shfl_xor(sum, off);
    attn_tab[q * 64 + t] = p / sum;   // pad lanes (t>=50) write 0

    float sq = 0.f;
    if (t < SD) {
#pragma unroll
      for (int i = 0; i < KD; ++i) sq = fmaf(qe[i], Ws[(64 + i) * SD + t], sq);
    }
    sq_tab[q * 64 + t] = (t < SD) ? sq : 0.f;
    return;
  }

  if (bid == NQ1) {  // ---- transposes ----
    for (int idx = t; idx < 64 * SD; idx += 64) {
      int i = idx / SD, j = idx % SD;
      WsT[j * 64 + i] = Ws[idx];
    }
    for (int idx = t; idx < SD * KK; idx += 64) {
      int j = idx / KK, c = idx % KK;
      WcT[c * SD + j] = Wc[idx];
    }
    return;
  }

  // ---- per-(q,r) erase/add, interleaved ----
  const int qr = bid - (NQ1 + 1);
  const int q = qr / KK, r = qr % KK;
  const int v = t;
  __shared__ float item[64];
  __shared__ float ves[64];
  item[v] = itab[q * KD + v];
  __syncthreads();

  float ve = bv[v];
#pragma unroll
  for (int i = 0; i < KD; ++i) ve = fmaf(item[i], Wv[i * VD + v], ve);
#pragma unroll
  for (int k = 0; k < KK; ++k) {
    float rf = fmaxf(0.f, 1.f - fabsf((float)k - (float)r) * 0.25f);
    ve = fmaf(rf, Wv[(KD + k) * VD + v], ve);
  }
  ves[v] = ve;
  __syncthreads();

  float se = be[v], sa = ba[v];
#pragma unroll
  for (int i = 0; i < VD; ++i) {
    float x = ves[i];
    se = fmaf(x, We[i * VD + v], se);
    sa = fmaf(x, Wa[i * VD + v], sa);
  }
  float ex = __expf(2.f * sa);
  ead_tab[qr * 128 + 2 * v]     = 1.f / (1.f + __expf(-se));
  ead_tab[qr * 128 + 2 * v + 1] = (ex - 1.f) / (ex + 1.f);
}

// ---------------- kernel 2: sequential scan, 8 waves, deep scalar prefetch ----------------
__global__ __launch_bounds__(NW * 64) void k_scan(
    const int* __restrict__ qs, const int* __restrict__ rs,
    const float* __restrict__ attn_tab, const float* __restrict__ ead_tab,
    const float* __restrict__ init_vm, float* __restrict__ reads) {
  const int b = blockIdx.x;
  const int tid = threadIdx.x;
  const int w = tid >> 6;       // wave id 0..7
  const int v = tid & 63;       // value column
  const int mbase = __builtin_amdgcn_readfirstlane(w * MPW);

  __shared__ float red[2][WIN][NW][66];

  const int* __restrict__ qb = qs + b * SS;
  const int* __restrict__ rb = rs + b * SS;

  float vm[MPW];
#pragma unroll
  for (int i = 0; i < MPW; ++i) {
    int m = mbase + i;
    vm[i] = (m < MM) ? init_vm[m * VD + v] : 0.f;
  }

  const char* __restrict__ atb = (const char*)attn_tab + (size_t)mbase * 4;
  const char* __restrict__ edb = (const char*)ead_tab + (size_t)v * 8;

  // rings: data (steps s0..s0+3), offsets (s0+4..s0+7), raw idx (s0+8..s0+11)
  float4 dx[4], dy[4];
  float2 de[4];
  int offA[4], offE[4];
  int qn[4], rn[4];

#pragma unroll
  for (int k = 0; k < 4; ++k) {
    int q = __builtin_amdgcn_readfirstlane(qb[k]);
    int r = __builtin_amdgcn_readfirstlane(rb[k]);
    int oA = q * 256, oE = (q * KK + r) * 512;
    dx[k] = *(const float4*)(atb + oA);
    dy[k] = *(const float4*)(atb + oA + 16);
    de[k] = *(const float2*)(edb + oE);
  }
#pragma unroll
  for (int k = 0; k < 4; ++k) {
    int q = __builtin_amdgcn_readfirstlane(qb[4 + k]);
    int r = __builtin_amdgcn_readfirstlane(rb[4 + k]);
    offA[k] = q * 256;
    offE[k] = (q * KK + r) * 512;
  }
#pragma unroll
  for (int k = 0; k < 4; ++k) {
    qn[k] = __builtin_amdgcn_readfirstlane(qb[8 + k]);
    rn[k] = __builtin_amdgcn_readfirstlane(rb[8 + k]);
  }

  float* __restrict__ outp = reads + (size_t)b * SS * 64;

  for (int s0 = 0; s0 < SS; s0 += 4) {
    if ((s0 & (WIN - 1)) == 0) {
      LGKM_BARRIER();
      if (s0 > 0) {
        const int wi = (s0 >> 4) - 1;
        const float (*rp)[NW][66] = red[wi & 1];
        const int rr = tid >> 5;             // 0..15
        const int cc = (tid & 31) * 2;       // 0..62
        float a0 = 0.f, a1 = 0.f;
#pragma unroll
        for (int wv = 0; wv < NW; ++wv) {
          float2 tt = *(const float2*)&rp[rr][wv][cc];
          a0 += tt.x; a1 += tt.y;
        }
        *(float2*)(outp + (size_t)(wi * WIN + rr) * 64 + cc) = make_float2(a0, a1);
      }
    }
    const int buf = (s0 >> 4) & 1;

#pragma unroll
    for (int k = 0; k < 4; ++k) {
      const int s = s0 + k;
      const float e = de[k].x, ad = de[k].y;
      float acc0 = 0.f, acc1 = 0.f;
      {
        float a0 = dx[k].x, a1 = dx[k].y, a2 = dx[k].z, a3 = dx[k].w;
        acc0 = fmaf(a0, vm[0], acc0);
        vm[0] = fmaf(a0, fmaf(-e, vm[0], ad), vm[0]);
        acc1 = fmaf(a1, vm[1], acc1);
        vm[1] = fmaf(a1, fmaf(-e, vm[1], ad), vm[1]);
        acc0 = fmaf(a2, vm[2], acc0);
        vm[2] = fmaf(a2, fmaf(-e, vm[2], ad), vm[2]);
        acc1 = fmaf(a3, vm[3], acc1);
        vm[3] = fmaf(a3, fmaf(-e, vm[3], ad), vm[3]);
      }
      {
        float a0 = dy[k].x, a1 = dy[k].y, a2 = dy[k].z, a3 = dy[k].w;
        acc0 = fmaf(a0, vm[4], acc0);
        vm[4] = fmaf(a0, fmaf(-e, vm[4], ad), vm[4]);
        acc1 = fmaf(a1, vm[5], acc1);
        vm[5] = fmaf(a1, fmaf(-e, vm[5], ad), vm[5]);
        acc0 = fmaf(a2, vm[6], acc0);
        vm[6] = fmaf(a2, fmaf(-e, vm[6], ad), vm[6]);
        acc1 = fmaf(a3, vm[7], acc1);
        vm[7] = fmaf(a3, fmaf(-e, vm[7], ad), vm[7]);
      }
      red[buf][s & (WIN - 1)][w][v] = acc0 + acc1;

      // refill data slot k for step s+4 (offsets already in regs)
      dx[k] = *(const float4*)(atb + offA[k]);
      dy[k] = *(const float4*)(atb + offA[k] + 16);
      de[k] = *(const float2*)(edb + offE[k]);

      // compute offsets for step s+8 from idx ring
      offA[k] = qn[k] * 256;
      offE[k] = (qn[k] * KK + rn[k]) * 512;

      // load raw idx for step s+12
      int tnext = s + 12;
      tnext = (tnext < SS) ? tnext : 0;
      qn[k] = __builtin_amdgcn_readfirstlane(qb[tnext]);
      rn[k] = __builtin_amdgcn_readfirstlane(rb[tnext]);
    }
  }

  // ---- tail flush: window 31 = steps 496..499, buffer 1 ----
  LGKM_BARRIER();
  {
    const int rr = tid >> 5;
    const int cc = (tid & 31) * 2;
    if (rr < (SS & (WIN - 1))) {
      const float (*rp)[NW][66] = red[(SS >> 4) & 1];
      float a0 = 0.f, a1 = 0.f;
#pragma unroll
      for (int wv = 0; wv < NW; ++wv) {
        float2 tt = *(const float2*)&rp[rr][wv][cc];
        a0 += tt.x; a1 += tt.y;
      }
      *(float2*)(outp + (size_t)((SS & ~(WIN - 1)) + rr) * 64 + cc) = make_float2(a0, a1);
    }
  }
}

// ---------------- kernel 3: summary + logits + softmax ----------------
__global__ __launch_bounds__(64) void k_out(
    const float* __restrict__ reads, const int* __restrict__ qs,
    const float* __restrict__ sq_tab, const float* __restrict__ WsT,
    const float* __restrict__ bs, const float* __restrict__ WcT,
    const float* __restrict__ bc,
    float* __restrict__ out_logits, float* __restrict__ out_probs) {
  __shared__ float xs[64 * 65];
  const int lane = threadIdx.x;
  const long rowbase = (long)blockIdx.x * 64;
  const float* __restrict__ src = reads + rowbase * 64;

#pragma unroll 8
  for (int it = 0; it < 64; ++it)
    xs[it * 65 + lane] = src[it * 64 + lane];
  __syncthreads();

  float x[64];
#pragma unroll
  for (int i = 0; i < 64; ++i) x[i] = xs[lane * 65 + i];

  const long row = rowbase + lane;
  const int q = qs[row];
  const float* __restrict__ sqrow = sq_tab + (long)q * 64;

  float sm[SD];
#pragma unroll
  for (int j = 0; j < SD; ++j) {
    float acc = bs[j] + sqrow[j];
    const float* __restrict__ wrow = WsT + j * 64;  // uniform -> s_load
#pragma unroll
    for (int i = 0; i < 64; ++i) acc = fmaf(x[i], wrow[i], acc);
    float ex = __expf(2.f * acc);
    sm[j] = (ex - 1.f) / (ex + 1.f);
  }

  float lg[KK];
#pragma unroll
  for (int c = 0; c < KK; ++c) {
    float acc = bc[c];
    const float* __restrict__ wrow = WcT + c * SD;  // uniform -> s_load
#pragma unroll
    for (int j = 0; j < SD; ++j) acc = fmaf(sm[j], wrow[j], acc);
    lg[c] = acc;
  }

  float mx = lg[0];
#pragma unroll
  for (int c = 1; c < KK; ++c) mx = fmaxf(mx, lg[c]);
  float p[KK], sum = 0.f;
#pragma unroll
  for (int c = 0; c < KK; ++c) { p[c] = __expf(lg[c] - mx); sum += p[c]; }
  float inv = 1.f / sum;
#pragma unroll
  for (int c = 0; c < KK; ++c) {
    out_logits[row * KK + c] = lg[c];
    out_probs[row * KK + c] = p[c] * inv;
  }
}

extern "C" void kernel_launch(void* const* d_in, const int* in_sizes, int n_in,
                              void* d_out, int out_size, void* d_ws, size_t ws_size,
                              hipStream_t stream) {
  const int*   questions  = (const int*)  d_in[0];
  const int*   responses  = (const int*)  d_in[1];
  const float* q_table    = (const float*)d_in[2];
  const float* item_table = (const float*)d_in[3];
  const float* Wv         = (const float*)d_in[4];
  const float* bv         = (const float*)d_in[5];
  const float* key_mem    = (const float*)d_in[6];
  const float* init_vm    = (const float*)d_in[7];
  const float* We         = (const float*)d_in[8];
  const float* be         = (const float*)d_in[9];
  const float* Wa         = (const float*)d_in[10];
  const float* ba         = (const float*)d_in[11];
  const float* Ws         = (const float*)d_in[12];
  const float* bs         = (const float*)d_in[13];
  const float* Wc         = (const float*)d_in[14];
  const float* bc         = (const float*)d_in[15];

  float* ws       = (float*)d_ws;
  float* attn_tab = ws + OFF_ATTN;
  float* sq_tab   = ws + OFF_SQ;
  float* ead_tab  = ws + OFF_EAD;
  float* WsT      = ws + OFF_WST;
  float* WcT      = ws + OFF_WCT;
  float* reads    = ws + OFF_READS;

  float* out_logits = (float*)d_out;
  float* out_probs  = out_logits + (size_t)BB * SS * KK;

  hipLaunchKernelGGL(k_tabs, dim3(NQ1 + 1 + NQ1 * KK), dim3(64), 0, stream,
                     q_table, item_table, key_mem, Wv, bv, We, be, Wa, ba, Ws, Wc,
                     attn_tab, sq_tab, ead_tab, WsT, WcT);
  hipLaunchKernelGGL(k_scan, dim3(BB), dim3(NW * 64), 0, stream,
                     questions, responses, attn_tab, ead_tab, init_vm, reads);
  hipLaunchKernelGGL(k_out, dim3(BB * SS / 64), dim3(64), 0, stream,
                     reads, questions, sq_tab, WsT, bs, WcT, bc,
                     out_logits, out_probs);
}

// Round 5
// 196.178 us; speedup vs baseline: 1.7960x; 1.1939x over previous
//
#include <hip/hip_runtime.h>
#include <hip/hip_bf16.h>
#include <math.h>

// Problem constants
#define NQ1 1001      // NQ+1 rows in embed tables
#define KK 5
#define MM 50
#define KD 64
#define VD 64
#define SD 50
#define BB 512
#define SS 500

#define NW 8          // waves per scan block
#define MPW 8         // memory slots per wave (padded 64 total)
#define WIN 8         // scan steps per window
#define NWIN 62       // full windows (62*8 = 496; tail = 4 steps)

// Workspace layout (in floats)
#define OFF_ATTN   0                        // [1001][64] attn rows, cols 50..63 = 0
#define OFF_SQ     (OFF_ATTN + NQ1*64)      // [1001][64] q_embed @ Ws[64:128]
#define OFF_EAD    (OFF_SQ   + NQ1*64)      // [5005][128] interleaved (e,ad) per v
#define OFF_WST    (OFF_EAD  + NQ1*KK*128)  // [50][64] transposed top of Ws
#define OFF_WCT    (OFF_WST  + SD*64)       // [5][50] transposed Wc (pad to 256)
#define OFF_READS  (OFF_WCT  + 256)         // [512*500][64]

#define LGKM_BARRIER() asm volatile("s_waitcnt lgkmcnt(0)\n\ts_barrier" ::: "memory")

// ---------------- kernel 1: all tables (qtab softmax+Sq, transposes, ead) ----------------
__global__ __launch_bounds__(64) void k_tabs(
    const float* __restrict__ qtab, const float* __restrict__ itab,
    const float* __restrict__ keymem,
    const float* __restrict__ Wv, const float* __restrict__ bv,
    const float* __restrict__ We, const float* __restrict__ be,
    const float* __restrict__ Wa, const float* __restrict__ ba,
    const float* __restrict__ Ws, const float* __restrict__ Wc,
    float* __restrict__ attn_tab, float* __restrict__ sq_tab,
    float* __restrict__ ead_tab, float* __restrict__ WsT, float* __restrict__ WcT) {
  const int bid = blockIdx.x;
  const int t = threadIdx.x;

  if (bid < NQ1) {  // ---- per-question: attn softmax row + sq row ----
    const int q = bid;
    __shared__ float qe[64];
    qe[t] = qtab[q * KD + t];
    __syncthreads();

    float dot = 0.f;
    if (t < MM) {
#pragma unroll
      for (int i = 0; i < KD; ++i) dot = fmaf(qe[i], keymem[t * KD + i], dot);
    }
    float xv = (t < MM) ? dot : -1e30f;
#pragma unroll
    for (int off = 32; off; off >>= 1) xv = fmaxf(xv, __shfl_xor(xv, off));
    float p = (t < MM) ? __expf(dot - xv) : 0.f;
    float sum = p;
#pragma unroll
    for (int off = 32; off; off >>= 1) sum += __shfl_xor(sum, off);
    attn_tab[q * 64 + t] = p / sum;   // pad lanes (t>=50) write 0

    float sq = 0.f;
    if (t < SD) {
#pragma unroll
      for (int i = 0; i < KD; ++i) sq = fmaf(qe[i], Ws[(64 + i) * SD + t], sq);
    }
    sq_tab[q * 64 + t] = (t < SD) ? sq : 0.f;
    return;
  }

  if (bid == NQ1) {  // ---- transposes ----
    for (int idx = t; idx < 64 * SD; idx += 64) {
      int i = idx / SD, j = idx % SD;
      WsT[j * 64 + i] = Ws[idx];
    }
    for (int idx = t; idx < SD * KK; idx += 64) {
      int j = idx / KK, c = idx % KK;
      WcT[c * SD + j] = Wc[idx];
    }
    return;
  }

  // ---- per-(q,r) erase/add, interleaved ----
  const int qr = bid - (NQ1 + 1);
  const int q = qr / KK, r = qr % KK;
  const int v = t;
  __shared__ float item[64];
  __shared__ float ves[64];
  item[v] = itab[q * KD + v];
  __syncthreads();

  float ve = bv[v];
#pragma unroll
  for (int i = 0; i < KD; ++i) ve = fmaf(item[i], Wv[i * VD + v], ve);
#pragma unroll
  for (int k = 0; k < KK; ++k) {
    float rf = fmaxf(0.f, 1.f - fabsf((float)k - (float)r) * 0.25f);
    ve = fmaf(rf, Wv[(KD + k) * VD + v], ve);
  }
  ves[v] = ve;
  __syncthreads();

  float se = be[v], sa = ba[v];
#pragma unroll
  for (int i = 0; i < VD; ++i) {
    float x = ves[i];
    se = fmaf(x, We[i * VD + v], se);
    sa = fmaf(x, Wa[i * VD + v], sa);
  }
  float ex = __expf(2.f * sa);
  ead_tab[qr * 128 + 2 * v]     = 1.f / (1.f + __expf(-se));
  ead_tab[qr * 128 + 2 * v + 1] = (ex - 1.f) / (ex + 1.f);
}

// ---------------- kernel 2: sequential scan, window-LDS-staged tables ----------------
__global__ __launch_bounds__(NW * 64) void k_scan(
    const int* __restrict__ qs, const int* __restrict__ rs,
    const float* __restrict__ attn_tab, const float* __restrict__ ead_tab,
    const float* __restrict__ init_vm, float* __restrict__ reads) {
  const int b = blockIdx.x;
  const int tid = threadIdx.x;
  const int w = tid >> 6;       // wave id 0..7 (also: staging row, flush row)
  const int v = tid & 63;       // value column
  const int mbase = w * MPW;

  __shared__ float red[2][WIN][NW][64];    // 32 KB partial read sums
  __shared__ float abuf[2][WIN][64];       // 4 KB attn rows
  __shared__ float ebuf[2][WIN][64];       // 4 KB erase rows
  __shared__ float adbuf[2][WIN][64];      // 4 KB add rows

  const int* __restrict__ qb = qs + b * SS;
  const int* __restrict__ rb = rs + b * SS;
  float* __restrict__ outp = reads + (size_t)b * SS * 64;

  // ---- prologue: stage window 0 directly; preload q/r for window 1 ----
  {
    int qp = qb[w], rp = rb[w];
    abuf[0][w][v] = attn_tab[qp * 64 + v];
    float2 ep = *(const float2*)(ead_tab + (qp * KK + rp) * 128 + 2 * v);
    ebuf[0][w][v] = ep.x;
    adbuf[0][w][v] = ep.y;
  }
  int q1 = qb[8 + w], r1 = rb[8 + w];    // window-1 indices (row w)

  float vm[MPW];
#pragma unroll
  for (int i = 0; i < MPW; ++i) {
    int m = mbase + i;
    vm[i] = (m < MM) ? init_vm[m * VD + v] : 0.f;
  }
  __syncthreads();

  float4 arx[2], ary[2];
  float ere[2], era[2];

#define PRELOAD(buf_) {                                              \
    const float* ab0 = &abuf[buf_][0][mbase];                        \
    arx[0] = *(const float4*)ab0;  ary[0] = *(const float4*)(ab0+4); \
    const float* ab1 = &abuf[buf_][1][mbase];                        \
    arx[1] = *(const float4*)ab1;  ary[1] = *(const float4*)(ab1+4); \
    ere[0] = ebuf[buf_][0][v];  era[0] = adbuf[buf_][0][v];          \
    ere[1] = ebuf[buf_][1][v];  era[1] = adbuf[buf_][1][v];          \
  }

#define STEP(buf_, kk) {                                             \
    float4 ax = arx[(kk)&1]; float4 ay = ary[(kk)&1];                \
    float ee = ere[(kk)&1];  float aa = era[(kk)&1];                 \
    if ((kk) < WIN - 2) {                                            \
      const float* abn = &abuf[buf_][(kk)+2][mbase];                 \
      arx[(kk)&1] = *(const float4*)abn;                             \
      ary[(kk)&1] = *(const float4*)(abn+4);                         \
      ere[(kk)&1] = ebuf[buf_][(kk)+2][v];                           \
      era[(kk)&1] = adbuf[buf_][(kk)+2][v];                          \
    }                                                                \
    float acc0 = 0.f, acc1 = 0.f;                                    \
    acc0 = fmaf(ax.x, vm[0], acc0);                                  \
    vm[0] = fmaf(ax.x, fmaf(-ee, vm[0], aa), vm[0]);                 \
    acc1 = fmaf(ax.y, vm[1], acc1);                                  \
    vm[1] = fmaf(ax.y, fmaf(-ee, vm[1], aa), vm[1]);                 \
    acc0 = fmaf(ax.z, vm[2], acc0);                                  \
    vm[2] = fmaf(ax.z, fmaf(-ee, vm[2], aa), vm[2]);                 \
    acc1 = fmaf(ax.w, vm[3], acc1);                                  \
    vm[3] = fmaf(ax.w, fmaf(-ee, vm[3], aa), vm[3]);                 \
    acc0 = fmaf(ay.x, vm[4], acc0);                                  \
    vm[4] = fmaf(ay.x, fmaf(-ee, vm[4], aa), vm[4]);                 \
    acc1 = fmaf(ay.y, vm[5], acc1);                                  \
    vm[5] = fmaf(ay.y, fmaf(-ee, vm[5], aa), vm[5]);                 \
    acc0 = fmaf(ay.z, vm[6], acc0);                                  \
    vm[6] = fmaf(ay.z, fmaf(-ee, vm[6], aa), vm[6]);                 \
    acc1 = fmaf(ay.w, vm[7], acc1);                                  \
    vm[7] = fmaf(ay.w, fmaf(-ee, vm[7], aa), vm[7]);                 \
    red[buf_][kk][w][v] = acc0 + acc1;                               \
  }

#define FLUSH(pbuf_, baserow_) {                                     \
    float sum = 0.f;                                                 \
    _Pragma("unroll")                                                \
    for (int wv = 0; wv < NW; ++wv) sum += red[pbuf_][w][wv][v];     \
    outp[(size_t)((baserow_) + w) * 64 + v] = sum;                   \
  }

  for (int wi = 0; wi < NWIN; ++wi) {
    const int buf = wi & 1;
    const int nb = buf ^ 1;

    // 1. preload register rings for steps 0,1 of this window
    PRELOAD(buf);

    // 2. flush previous window (reads red[nb], drained before next barrier)
    if (wi > 0) FLUSH(nb, (wi - 1) * WIN);

    // 3. staging issue for window wi+1 (q1/r1 loaded a full window ago ->
    //    gather addresses ready; all VMEM, not drained by lgkm barrier)
    float a_st = attn_tab[q1 * 64 + v];
    float2 e_st = *(const float2*)(ead_tab + (q1 * KK + r1) * 128 + 2 * v);
    int i2 = (wi + 2) * WIN + w;
    i2 = (i2 < SS) ? i2 : (SS - 1);
    int q2 = qb[i2], r2 = rb[i2];

    // 4. compute 8 steps
    STEP(buf, 0); STEP(buf, 1); STEP(buf, 2); STEP(buf, 3);
    STEP(buf, 4); STEP(buf, 5); STEP(buf, 6); STEP(buf, 7);

    // 5. staging writes (compiler inserts vmcnt wait for gather data only)
    abuf[nb][w][v] = a_st;
    ebuf[nb][w][v] = e_st.x;
    adbuf[nb][w][v] = e_st.y;
    q1 = q2; r1 = r2;

    // 6. window barrier: lgkm (LDS) drain only, VMEM stays in flight
    LGKM_BARRIER();
  }

  // ---- tail: window 62 = steps 496..499, buf 0 ----
  {
    PRELOAD(0);
    FLUSH(1, (NWIN - 1) * WIN);          // flush window 61
    STEP(0, 0); STEP(0, 1); STEP(0, 2); STEP(0, 3);
    LGKM_BARRIER();
    if (w < (SS - NWIN * WIN)) {
      float sum = 0.f;
#pragma unroll
      for (int wv = 0; wv < NW; ++wv) sum += red[0][w][wv][v];
      outp[(size_t)(NWIN * WIN + w) * 64 + v] = sum;
    }
  }
#undef PRELOAD
#undef STEP
#undef FLUSH
}

// ---------------- kernel 3: summary + logits + softmax ----------------
__global__ __launch_bounds__(64) void k_out(
    const float* __restrict__ reads, const int* __restrict__ qs,
    const float* __restrict__ sq_tab, const float* __restrict__ WsT,
    const float* __restrict__ bs, const float* __restrict__ WcT,
    const float* __restrict__ bc,
    float* __restrict__ out_logits, float* __restrict__ out_probs) {
  __shared__ float xs[64 * 65];
  const int lane = threadIdx.x;
  const long rowbase = (long)blockIdx.x * 64;
  const float* __restrict__ src = reads + rowbase * 64;

#pragma unroll 8
  for (int it = 0; it < 64; ++it)
    xs[it * 65 + lane] = src[it * 64 + lane];
  __syncthreads();

  float x[64];
#pragma unroll
  for (int i = 0; i < 64; ++i) x[i] = xs[lane * 65 + i];

  const long row = rowbase + lane;
  const int q = qs[row];
  const float* __restrict__ sqrow = sq_tab + (long)q * 64;

  float sm[SD];
#pragma unroll
  for (int j = 0; j < SD; ++j) {
    float acc = bs[j] + sqrow[j];
    const float* __restrict__ wrow = WsT + j * 64;  // uniform -> s_load
#pragma unroll
    for (int i = 0; i < 64; ++i) acc = fmaf(x[i], wrow[i], acc);
    float ex = __expf(2.f * acc);
    sm[j] = (ex - 1.f) / (ex + 1.f);
  }

  float lg[KK];
#pragma unroll
  for (int c = 0; c < KK; ++c) {
    float acc = bc[c];
    const float* __restrict__ wrow = WcT + c * SD;  // uniform -> s_load
#pragma unroll
    for (int j = 0; j < SD; ++j) acc = fmaf(sm[j], wrow[j], acc);
    lg[c] = acc;
  }

  float mx = lg[0];
#pragma unroll
  for (int c = 1; c < KK; ++c) mx = fmaxf(mx, lg[c]);
  float p[KK], sum = 0.f;
#pragma unroll
  for (int c = 0; c < KK; ++c) { p[c] = __expf(lg[c] - mx); sum += p[c]; }
  float inv = 1.f / sum;
#pragma unroll
  for (int c = 0; c < KK; ++c) {
    out_logits[row * KK + c] = lg[c];
    out_probs[row * KK + c] = p[c] * inv;
  }
}

extern "C" void kernel_launch(void* const* d_in, const int* in_sizes, int n_in,
                              void* d_out, int out_size, void* d_ws, size_t ws_size,
                              hipStream_t stream) {
  const int*   questions  = (const int*)  d_in[0];
  const int*   responses  = (const int*)  d_in[1];
  const float* q_table    = (const float*)d_in[2];
  const float* item_table = (const float*)d_in[3];
  const float* Wv         = (const float*)d_in[4];
  const float* bv         = (const float*)d_in[5];
  const float* key_mem    = (const float*)d_in[6];
  const float* init_vm    = (const float*)d_in[7];
  const float* We         = (const float*)d_in[8];
  const float* be         = (const float*)d_in[9];
  const float* Wa         = (const float*)d_in[10];
  const float* ba         = (const float*)d_in[11];
  const float* Ws         = (const float*)d_in[12];
  const float* bs         = (const float*)d_in[13];
  const float* Wc         = (const float*)d_in[14];
  const float* bc         = (const float*)d_in[15];

  float* ws       = (float*)d_ws;
  float* attn_tab = ws + OFF_ATTN;
  float* sq_tab   = ws + OFF_SQ;
  float* ead_tab  = ws + OFF_EAD;
  float* WsT      = ws + OFF_WST;
  float* WcT      = ws + OFF_WCT;
  float* reads    = ws + OFF_READS;

  float* out_logits = (float*)d_out;
  float* out_probs  = out_logits + (size_t)BB * SS * KK;

  hipLaunchKernelGGL(k_tabs, dim3(NQ1 + 1 + NQ1 * KK), dim3(64), 0, stream,
                     q_table, item_table, key_mem, Wv, bv, We, be, Wa, ba, Ws, Wc,
                     attn_tab, sq_tab, ead_tab, WsT, WcT);
  hipLaunchKernelGGL(k_scan, dim3(BB), dim3(NW * 64), 0, stream,
                     questions, responses, attn_tab, ead_tab, init_vm, reads);
  hipLaunchKernelGGL(k_out, dim3(BB * SS / 64), dim3(64), 0, stream,
                     reads, questions, sq_tab, WsT, bs, WcT, bc,
                     out_logits, out_probs);
}